// Round 9
// baseline (686.021 us; speedup 1.0000x reference)
//
#include <hip/hip_runtime.h>
#include <hip/hip_bf16.h>

#define N_ROWS 8192
#define DIM 256
#define TEMP_INV 20.0f
// exp(cos/T) = exp2(cos * 20*log2(e)); anchor rows are PRE-SCALED by this so
// the fused epilogue is a bare v_exp on the MFMA accumulator.
#define EXP_SCALE 28.853900817779268f

typedef __attribute__((ext_vector_type(8))) short bf16x8;
typedef __attribute__((ext_vector_type(4))) float f32x4;

// ---------------------------------------------------------------------------
// 1) Merged prep:
//    blocks [0,2048): anchor rows -- a_n = anc*EXP_SCALE/||anc|| (bf16),
//                     diag = cos(anc,pos)/TEMP (f32 originals), rowsum = 0.
//    blocks [2048,2560): P/N panels -- L2-normalize + transpose to k-major
//                     panels (32 cols; 16B chunk idx = k0*32+col, k0=k/8).
//    block 2559 thread 0 additionally zero-inits out[0].
// ---------------------------------------------------------------------------
__global__ void __launch_bounds__(256) prep_kernel(
    const float* __restrict__ anc, const float* __restrict__ pos,
    const float* __restrict__ neg, __hip_bfloat16* __restrict__ a_n,
    __hip_bfloat16* __restrict__ p_k, __hip_bfloat16* __restrict__ n_k,
    float* __restrict__ diag, float* __restrict__ rowsum,
    float* __restrict__ out) {
  __shared__ __align__(16) __hip_bfloat16 t[32 * DIM];   // 16KB (panel path)
  const int lane = threadIdx.x & 63;
  const int w = threadIdx.x >> 6;

  if (blockIdx.x < 2048) {                   // ---- anchor rows ----
    int wid = blockIdx.x * 4 + w;            // row 0..8191
    float4 a = reinterpret_cast<const float4*>(anc + (size_t)wid * DIM)[lane];
    float4 p = reinterpret_cast<const float4*>(pos + (size_t)wid * DIM)[lane];
    float d  = a.x * p.x + a.y * p.y + a.z * p.z + a.w * p.w;
    float na = a.x * a.x + a.y * a.y + a.z * a.z + a.w * a.w;
    float np = p.x * p.x + p.y * p.y + p.z * p.z + p.w * p.w;
#pragma unroll
    for (int m = 32; m; m >>= 1) {
      d  += __shfl_xor(d, m);
      na += __shfl_xor(na, m);
      np += __shfl_xor(np, m);
    }
    float rna = fmaxf(sqrtf(na), 1e-8f);
    float scale = EXP_SCALE / rna;
    union { __hip_bfloat16 h[4]; uint2 u; } pk;
    pk.h[0] = __float2bfloat16(a.x * scale);
    pk.h[1] = __float2bfloat16(a.y * scale);
    pk.h[2] = __float2bfloat16(a.z * scale);
    pk.h[3] = __float2bfloat16(a.w * scale);
    reinterpret_cast<uint2*>(a_n + (size_t)wid * DIM)[lane] = pk.u;
    if (lane == 0) {
      diag[wid] = TEMP_INV * d / (rna * fmaxf(sqrtf(np), 1e-8f));
      rowsum[wid] = 0.f;
    }
    return;
  }
  // ---- P/N k-major panels ----
  const int b = blockIdx.x - 2048;           // 0..511
  if (b == 511 && threadIdx.x == 0) out[0] = 0.f;
  const float* src = (b < 256) ? pos : neg;
  __hip_bfloat16* dst = (b < 256) ? p_k : n_k;
  const int pb = b & 255;
#pragma unroll
  for (int i = 0; i < 8; ++i) {
    int r = i * 4 + w;                       // row (col of B) within panel
    float4 v = reinterpret_cast<const float4*>(src + (size_t)(pb * 32 + r) * DIM)[lane];
    float ss = v.x * v.x + v.y * v.y + v.z * v.z + v.w * v.w;
#pragma unroll
    for (int m = 32; m; m >>= 1) ss += __shfl_xor(ss, m);
    float scale = 1.0f / fmaxf(sqrtf(ss), 1e-8f);
    union { __hip_bfloat16 h[4]; uint2 u; } pk;
    pk.h[0] = __float2bfloat16(v.x * scale);
    pk.h[1] = __float2bfloat16(v.y * scale);
    pk.h[2] = __float2bfloat16(v.z * scale);
    pk.h[3] = __float2bfloat16(v.w * scale);
    // lane holds k = 4*lane..4*lane+3  ->  k0 = lane>>1, half = lane&1
    char* p = (char*)t + ((((lane >> 1) * 32) + r) << 4) + ((lane & 1) << 3);
    *reinterpret_cast<uint2*>(p) = pk.u;
  }
  __syncthreads();
  const uint4* ts = reinterpret_cast<const uint4*>(t);
  uint4* outp = reinterpret_cast<uint4*>(dst + (size_t)pb * (32 * DIM));
#pragma unroll
  for (int j = 0; j < 4; ++j)
    outp[threadIdx.x + j * 256] = ts[threadIdx.x + j * 256];
}

// ---------------------------------------------------------------------------
// 2) Fused GEMM + row-wise sum(exp2(logit)).
//    Post-R8 diagnosis: MfmaUtil tracks waves/SIMD (R3: 3 waves -> 42%;
//    R5-R8: 2 waves -> 35-38%); launch_bounds(…,2) let the allocator use up
//    to 1024 regs/wave, capping residency at 2 waves/SIMD. Fixes:
//    (a) __launch_bounds__(512,4): force fit of 4 waves/SIMD (2 blocks/CU,
//        LDS 2x64KB <= 160KB; ~300 regs/wave needed <= 512 cap, no spill).
//    (b) Cross-phase REGISTER double-buffer of B-frags (bfA/bfB): ds_reads
//        for cluster c+1 issue before the MFMA burst of cluster c ->
//        load-use distance = one 32-MFMA cluster >= LDS latency; kills the
//        barrier-synchronized phase-start lgkm bubble.
//    Waits: panel it+1 is guaranteed complete at barrier(it) (steady
//    vmcnt(2), tail 0), so the late bfA prefetch of [it+1,cf0] is safe.
//    Ring-4 LDS slots; STAGE(it+3) after barrier(it) overwrites slot
//    (it-1)&3 whose reads retired before barrier(it). k-major panels ->
//    ds_reads linear-in-lane, 0 conflicts (R4-R8 verified).
//    MFMA 16x16x32_bf16 C layout: col=lane&15, row=(lane>>4)*4+q  [verified].
// ---------------------------------------------------------------------------
__global__ void __launch_bounds__(512, 4) fused_kernel(
    const __hip_bfloat16* __restrict__ a_n, const __hip_bfloat16* __restrict__ p_k,
    const __hip_bfloat16* __restrict__ n_k, float* __restrict__ rowsum) {
  __shared__ __align__(16) char smem[4 * 16384];   // ring of 4 x 16KB panels
  const int tid  = threadIdx.x;
  const int lane = tid & 63;
  const int w    = tid >> 6;          // 0..7
  const int rb   = blockIdx.x >> 5;   // 0..15 (512 rows each)
  const int cc   = blockIdx.x & 31;   // 0..31 (512 cols = 16 panels each)
  const char* B = (const char*)((cc < 16)
      ? (p_k + (size_t)cc * 16 * (32 * DIM))
      : (n_k + (size_t)(cc - 16) * 16 * (32 * DIM)));
  const int row0 = rb * 512 + w * 64;
  const int ar = lane & 15;           // fragment row/col index
  const int g  = lane >> 4;           // k-group within fragment
  const int vbase = (g << 9) + (ar << 4);  // lane byte-offset within a panel

  // A fragments: 64 rows x K=256, pinned resident (AGPR side of the file).
  bf16x8 afrag[4][8];
#pragma unroll
  for (int rf = 0; rf < 4; ++rf)
#pragma unroll
    for (int kk = 0; kk < 8; ++kk) {
      afrag[rf][kk] = *reinterpret_cast<const bf16x8*>(
          a_n + (size_t)(row0 + rf * 16 + ar) * DIM + kk * 32 + g * 8);
      asm volatile("" : "+v"(afrag[rf][kk]));   // non-remat def: stays resident
    }

  // Stage panel `p` (16KB contiguous) into ring slot p&3: 2 loads/wave.
#define STAGE(p)                                                               \
  {                                                                            \
    _Pragma("unroll")                                                          \
    for (int j = 0; j < 2; ++j) {                                              \
      const int L = (w << 1) | j;                                              \
      const char* src = B + ((size_t)(p) << 14) + (L << 10) + (lane << 4);     \
      char* dst = (char*)smem + (((p) & 3) << 14) + (L << 10);                 \
      __builtin_amdgcn_global_load_lds(                                        \
          (const __attribute__((address_space(1))) void*)src,                  \
          (__attribute__((address_space(3))) void*)dst, 16, 0, 0);             \
    }                                                                          \
  }

  // 32 MFMA on buffer `bf` + exp2 epilogue into psum.
#define MFMA_CLUSTER(bf)                                                       \
  {                                                                            \
    f32x4 acc[4];                                                              \
    _Pragma("unroll")                                                          \
    for (int rf = 0; rf < 4; ++rf) acc[rf] = (f32x4){0.f, 0.f, 0.f, 0.f};      \
    __builtin_amdgcn_s_setprio(1);                                             \
    _Pragma("unroll")                                                          \
    for (int kk = 0; kk < 8; ++kk)                                             \
      _Pragma("unroll")                                                        \
      for (int rf = 0; rf < 4; ++rf)                                           \
        acc[rf] = __builtin_amdgcn_mfma_f32_16x16x32_bf16(afrag[rf][kk], bf[kk], acc[rf], 0, 0, 0); \
    __builtin_amdgcn_s_setprio(0);                                             \
    _Pragma("unroll")                                                          \
    for (int rf = 0; rf < 4; ++rf)                                             \
      _Pragma("unroll")                                                        \
      for (int q = 0; q < 4; ++q)                                              \
        psum[rf][q] += __builtin_amdgcn_exp2f(acc[rf][q]);                     \
  }

  float psum[4][4];
#pragma unroll
  for (int rf = 0; rf < 4; ++rf)
#pragma unroll
    for (int q = 0; q < 4; ++q) psum[rf][q] = 0.f;

  bf16x8 bfA[8], bfB[8];

  STAGE(0);
  STAGE(1);
  STAGE(2);   // 6 loads/wave outstanding
  asm volatile("s_waitcnt vmcnt(4)" ::: "memory");   // panel 0 landed
  __builtin_amdgcn_s_barrier();
  {  // preload bfA <- [panel 0, cf0]
    const char* pb = smem + vbase;
#pragma unroll
    for (int kk = 0; kk < 8; ++kk)
      bfA[kk] = *reinterpret_cast<const bf16x8*>(pb + (kk << 11));
  }

  for (int it = 0; it < 16; ++it) {
    // Counted waits: guarantee panels <= it+1 complete; newer stay in flight.
    if (it <= 13) asm volatile("s_waitcnt vmcnt(2)" ::: "memory");
    else          asm volatile("s_waitcnt vmcnt(0)" ::: "memory");
    __builtin_amdgcn_s_barrier();
    const char* pbase = smem + ((it & 3) << 14) + vbase;
    // Read bfB <- [it, cf1] (consumed one cluster later).
#pragma unroll
    for (int kk = 0; kk < 8; ++kk)
      bfB[kk] = *reinterpret_cast<const bf16x8*>(pbase + (kk << 11) + 256);
    if (it <= 12) STAGE(it + 3);
    MFMA_CLUSTER(bfA);            // cluster [it, cf0]
    if (it < 15) {                // prefetch bfA <- [it+1, cf0] (panel complete)
      const char* nbase = smem + (((it + 1) & 3) << 14) + vbase;
#pragma unroll
      for (int kk = 0; kk < 8; ++kk)
        bfA[kk] = *reinterpret_cast<const bf16x8*>(nbase + (kk << 11));
    }
    MFMA_CLUSTER(bfB);            // cluster [it, cf1]
  }

  // Reduce over the 16 column-lanes (vary ar, keep g) and accumulate per row.
#pragma unroll
  for (int rf = 0; rf < 4; ++rf)
#pragma unroll
    for (int q = 0; q < 4; ++q) {
      float s = psum[rf][q];
      s += __shfl_xor(s, 1);
      s += __shfl_xor(s, 2);
      s += __shfl_xor(s, 4);
      s += __shfl_xor(s, 8);
      if (ar == 0)
        atomicAdd(rowsum + row0 + rf * 16 + g * 4 + q, s);
    }
#undef STAGE
#undef MFMA_CLUSTER
}

// ---------------------------------------------------------------------------
// 3) loss: grid 16 x 512 thr, one row per thread;
//    out[0] (+)= block-partials / N   (out zero-initialized in prep).
// ---------------------------------------------------------------------------
__global__ void __launch_bounds__(512) loss_kernel(
    const float* __restrict__ rowsum, const float* __restrict__ diag,
    float* __restrict__ out) {
  __shared__ float sh[8];
  int i = blockIdx.x * 512 + threadIdx.x;    // exactly covers 8192 rows
  float acc = logf(rowsum[i]) - diag[i];
#pragma unroll
  for (int m = 32; m; m >>= 1) acc += __shfl_xor(acc, m);
  if ((threadIdx.x & 63) == 0) sh[threadIdx.x >> 6] = acc;
  __syncthreads();
  if (threadIdx.x == 0) {
    float t = 0.f;
#pragma unroll
    for (int j = 0; j < 8; ++j) t += sh[j];
    atomicAdd(out, t / (float)N_ROWS);
  }
}

// ---------------------------------------------------------------------------
extern "C" void kernel_launch(void* const* d_in, const int* in_sizes, int n_in,
                              void* d_out, int out_size, void* d_ws, size_t ws_size,
                              hipStream_t stream) {
  const float* anc = (const float*)d_in[0];
  const float* pos = (const float*)d_in[1];
  const float* neg = (const float*)d_in[2];
  char* ws = (char*)d_ws;
  __hip_bfloat16* a_n = (__hip_bfloat16*)ws;                 // [8192][256] bf16 row-major
  __hip_bfloat16* p_k = a_n + (size_t)N_ROWS * DIM;          // k-major panels
  __hip_bfloat16* n_k = p_k + (size_t)N_ROWS * DIM;
  float* diag = (float*)(ws + (size_t)3 * N_ROWS * DIM * 2); // 8192 f32
  float* rowsum = diag + N_ROWS;                             // 8192 f32
  float* out = (float*)d_out;

  prep_kernel<<<2048 + 512, 256, 0, stream>>>(anc, pos, neg, a_n, p_k, n_k, diag, rowsum, out);
  fused_kernel<<<16 * 32, 512, 0, stream>>>(a_n, p_k, n_k, rowsum);
  loss_kernel<<<16, 512, 0, stream>>>(rowsum, diag, out);
}

// Round 10
// 84.412 us; speedup vs baseline: 8.1271x; 8.1271x over previous
//
#include <hip/hip_runtime.h>
#include <hip/hip_bf16.h>

#define N_ROWS 8192
#define DIM 256
#define TEMP_INV 20.0f
// exp(cos/T) = exp2(cos * 20*log2(e)); anchor rows are PRE-SCALED by this so
// the fused epilogue is a bare v_exp on the MFMA accumulator.
#define EXP_SCALE 28.853900817779268f

typedef __attribute__((ext_vector_type(8))) short bf16x8;
typedef __attribute__((ext_vector_type(4))) float f32x4;

// ---------------------------------------------------------------------------
// 1) Merged prep:
//    blocks [0,2048): anchor rows -- a_n = anc*EXP_SCALE/||anc|| (bf16),
//                     diag = cos(anc,pos)/TEMP (f32 originals), rowsum = 0.
//    blocks [2048,2560): P/N panels -- L2-normalize + transpose to k-major
//                     panels (32 cols; 16B chunk idx = k0*32+col, k0=k/8).
//    block 2559 thread 0 additionally zero-inits out[0].
// ---------------------------------------------------------------------------
__global__ void __launch_bounds__(256) prep_kernel(
    const float* __restrict__ anc, const float* __restrict__ pos,
    const float* __restrict__ neg, __hip_bfloat16* __restrict__ a_n,
    __hip_bfloat16* __restrict__ p_k, __hip_bfloat16* __restrict__ n_k,
    float* __restrict__ diag, float* __restrict__ rowsum,
    float* __restrict__ out) {
  __shared__ __align__(16) __hip_bfloat16 t[32 * DIM];   // 16KB (panel path)
  const int lane = threadIdx.x & 63;
  const int w = threadIdx.x >> 6;

  if (blockIdx.x < 2048) {                   // ---- anchor rows ----
    int wid = blockIdx.x * 4 + w;            // row 0..8191
    float4 a = reinterpret_cast<const float4*>(anc + (size_t)wid * DIM)[lane];
    float4 p = reinterpret_cast<const float4*>(pos + (size_t)wid * DIM)[lane];
    float d  = a.x * p.x + a.y * p.y + a.z * p.z + a.w * p.w;
    float na = a.x * a.x + a.y * a.y + a.z * a.z + a.w * a.w;
    float np = p.x * p.x + p.y * p.y + p.z * p.z + p.w * p.w;
#pragma unroll
    for (int m = 32; m; m >>= 1) {
      d  += __shfl_xor(d, m);
      na += __shfl_xor(na, m);
      np += __shfl_xor(np, m);
    }
    float rna = fmaxf(sqrtf(na), 1e-8f);
    float scale = EXP_SCALE / rna;
    union { __hip_bfloat16 h[4]; uint2 u; } pk;
    pk.h[0] = __float2bfloat16(a.x * scale);
    pk.h[1] = __float2bfloat16(a.y * scale);
    pk.h[2] = __float2bfloat16(a.z * scale);
    pk.h[3] = __float2bfloat16(a.w * scale);
    reinterpret_cast<uint2*>(a_n + (size_t)wid * DIM)[lane] = pk.u;
    if (lane == 0) {
      diag[wid] = TEMP_INV * d / (rna * fmaxf(sqrtf(np), 1e-8f));
      rowsum[wid] = 0.f;
    }
    return;
  }
  // ---- P/N k-major panels ----
  const int b = blockIdx.x - 2048;           // 0..511
  if (b == 511 && threadIdx.x == 0) out[0] = 0.f;
  const float* src = (b < 256) ? pos : neg;
  __hip_bfloat16* dst = (b < 256) ? p_k : n_k;
  const int pb = b & 255;
#pragma unroll
  for (int i = 0; i < 8; ++i) {
    int r = i * 4 + w;                       // row (col of B) within panel
    float4 v = reinterpret_cast<const float4*>(src + (size_t)(pb * 32 + r) * DIM)[lane];
    float ss = v.x * v.x + v.y * v.y + v.z * v.z + v.w * v.w;
#pragma unroll
    for (int m = 32; m; m >>= 1) ss += __shfl_xor(ss, m);
    float scale = 1.0f / fmaxf(sqrtf(ss), 1e-8f);
    union { __hip_bfloat16 h[4]; uint2 u; } pk;
    pk.h[0] = __float2bfloat16(v.x * scale);
    pk.h[1] = __float2bfloat16(v.y * scale);
    pk.h[2] = __float2bfloat16(v.z * scale);
    pk.h[3] = __float2bfloat16(v.w * scale);
    // lane holds k = 4*lane..4*lane+3  ->  k0 = lane>>1, half = lane&1
    char* p = (char*)t + ((((lane >> 1) * 32) + r) << 4) + ((lane & 1) << 3);
    *reinterpret_cast<uint2*>(p) = pk.u;
  }
  __syncthreads();
  const uint4* ts = reinterpret_cast<const uint4*>(t);
  uint4* outp = reinterpret_cast<uint4*>(dst + (size_t)pb * (32 * DIM));
#pragma unroll
  for (int j = 0; j < 4; ++j)
    outp[threadIdx.x + j * 256] = ts[threadIdx.x + j * 256];
}

// ---------------------------------------------------------------------------
// 2) Fused GEMM + row-wise sum(exp2(logit)) -- epilogue-pipelined.
//    Post-R9 model: 2 waves/SIMD is a hard cap (A-resident = 128 regs;
//    512-reg SIMD file). The plateau (R5-R8) is the SERIAL per-cluster
//    epilogue: in-order wave stalls exp2 on the MFMA chain tail, then next
//    cluster's MFMAs wait behind the epilogue (~500cy serial vs 512cy pipe).
//    Fixes (all per-wave ILP, no occupancy change):
//    (a) acc ping-pong (accA/accB): cluster c's MFMAs interleave with
//        cluster c-1's exp2/psum (independent -> fills MFMA issue gaps).
//    (b) kk0 MFMA takes zerov as C -> no per-cluster acc zero-init.
//    (c) split-half B refill: bf0 (kk0-3) reloaded right after its last
//        consuming MFMA issues (WAR-safe, in-order), 5 slots before use;
//        same for bf1 -> no lgkm stall at cluster start.
//    (d) first-cluster dummy epilogue on zeroed accB (exp2(0)=1 per elem)
//        compensated by -1.0 at the reduction -> branch-free hot loop.
//    Ring-4 LDS (64KB), counted vmcnt(2) steady / 0 tail, ONE barrier per
//    panel. k-major panels -> ds_reads linear-in-lane, 0 conflicts.
//    MFMA 16x16x32_bf16 C layout: col=lane&15, row=(lane>>4)*4+q  [verified].
// ---------------------------------------------------------------------------
__global__ void __launch_bounds__(512, 2) fused_kernel(
    const __hip_bfloat16* __restrict__ a_n, const __hip_bfloat16* __restrict__ p_k,
    const __hip_bfloat16* __restrict__ n_k, float* __restrict__ rowsum) {
  __shared__ __align__(16) char smem[4 * 16384];   // ring of 4 x 16KB panels
  const int tid  = threadIdx.x;
  const int lane = tid & 63;
  const int w    = tid >> 6;          // 0..7
  const int rb   = blockIdx.x >> 5;   // 0..15 (512 rows each)
  const int cc   = blockIdx.x & 31;   // 0..31 (512 cols = 16 panels each)
  const char* B = (const char*)((cc < 16)
      ? (p_k + (size_t)cc * 16 * (32 * DIM))
      : (n_k + (size_t)(cc - 16) * 16 * (32 * DIM)));
  const int row0 = rb * 512 + w * 64;
  const int ar = lane & 15;           // fragment row/col index
  const int g  = lane >> 4;           // k-group within fragment
  const int vbase = (g << 9) + (ar << 4);  // lane byte-offset within a panel

  // A fragments: 64 rows x K=256, pinned resident.
  bf16x8 afrag[4][8];
#pragma unroll
  for (int rf = 0; rf < 4; ++rf)
#pragma unroll
    for (int kk = 0; kk < 8; ++kk) {
      afrag[rf][kk] = *reinterpret_cast<const bf16x8*>(
          a_n + (size_t)(row0 + rf * 16 + ar) * DIM + kk * 32 + g * 8);
      asm volatile("" : "+v"(afrag[rf][kk]));   // non-remat def: stays resident
    }

  // Stage panel `p` (16KB contiguous) into ring slot p&3: 2 loads/wave.
#define STAGE(p)                                                               \
  {                                                                            \
    _Pragma("unroll")                                                          \
    for (int j = 0; j < 2; ++j) {                                              \
      const int L = (w << 1) | j;                                              \
      const char* src = B + ((size_t)(p) << 14) + (L << 10) + (lane << 4);     \
      char* dst = (char*)smem + (((p) & 3) << 14) + (L << 10);                 \
      __builtin_amdgcn_global_load_lds(                                        \
          (const __attribute__((address_space(1))) void*)src,                  \
          (__attribute__((address_space(3))) void*)dst, 16, 0, 0);             \
    }                                                                          \
  }

#define LDV(p) (*reinterpret_cast<const bf16x8*>(p))
#define MM(A, Bf, C) __builtin_amdgcn_mfma_f32_16x16x32_bf16((A), (Bf), (C), 0, 0, 0)
#define EPI(ACCP, e) \
  psum[(e) >> 2][(e) & 3] += __builtin_amdgcn_exp2f(ACCP[(e) >> 2][(e) & 3])

  // One cluster (16 output cols, K=256 = 8 kk slots of 4 MFMA each).
  // Interleaved per slot: 4 MFMA (accC) + 2 epilogue elems (accP).
  // bf0 refilled after slot3 (its last consumer), bf1 after slot7 -> next
  // cluster's operands arrive ~5 slots (>=300cy) before first use.
#define CLUSTER(ACCC, ACCP, NEXTB)                                             \
  {                                                                            \
    ACCC[0] = MM(afrag[0][0], bf0[0], zerov);                                  \
    ACCC[1] = MM(afrag[1][0], bf0[0], zerov);                                  \
    ACCC[2] = MM(afrag[2][0], bf0[0], zerov);                                  \
    ACCC[3] = MM(afrag[3][0], bf0[0], zerov);                                  \
    EPI(ACCP, 0); EPI(ACCP, 1);                                                \
    ACCC[0] = MM(afrag[0][1], bf0[1], ACCC[0]);                                \
    ACCC[1] = MM(afrag[1][1], bf0[1], ACCC[1]);                                \
    ACCC[2] = MM(afrag[2][1], bf0[1], ACCC[2]);                                \
    ACCC[3] = MM(afrag[3][1], bf0[1], ACCC[3]);                                \
    EPI(ACCP, 2); EPI(ACCP, 3);                                                \
    ACCC[0] = MM(afrag[0][2], bf0[2], ACCC[0]);                                \
    ACCC[1] = MM(afrag[1][2], bf0[2], ACCC[1]);                                \
    ACCC[2] = MM(afrag[2][2], bf0[2], ACCC[2]);                                \
    ACCC[3] = MM(afrag[3][2], bf0[2], ACCC[3]);                                \
    EPI(ACCP, 4); EPI(ACCP, 5);                                                \
    ACCC[0] = MM(afrag[0][3], bf0[3], ACCC[0]);                                \
    ACCC[1] = MM(afrag[1][3], bf0[3], ACCC[1]);                                \
    ACCC[2] = MM(afrag[2][3], bf0[3], ACCC[2]);                                \
    ACCC[3] = MM(afrag[3][3], bf0[3], ACCC[3]);                                \
    EPI(ACCP, 6); EPI(ACCP, 7);                                                \
    bf0[0] = LDV((NEXTB));                                                     \
    bf0[1] = LDV((NEXTB) + 2048);                                              \
    bf0[2] = LDV((NEXTB) + 4096);                                              \
    bf0[3] = LDV((NEXTB) + 6144);                                              \
    ACCC[0] = MM(afrag[0][4], bf1[0], ACCC[0]);                                \
    ACCC[1] = MM(afrag[1][4], bf1[0], ACCC[1]);                                \
    ACCC[2] = MM(afrag[2][4], bf1[0], ACCC[2]);                                \
    ACCC[3] = MM(afrag[3][4], bf1[0], ACCC[3]);                                \
    EPI(ACCP, 8); EPI(ACCP, 9);                                                \
    ACCC[0] = MM(afrag[0][5], bf1[1], ACCC[0]);                                \
    ACCC[1] = MM(afrag[1][5], bf1[1], ACCC[1]);                                \
    ACCC[2] = MM(afrag[2][5], bf1[1], ACCC[2]);                                \
    ACCC[3] = MM(afrag[3][5], bf1[1], ACCC[3]);                                \
    EPI(ACCP, 10); EPI(ACCP, 11);                                              \
    ACCC[0] = MM(afrag[0][6], bf1[2], ACCC[0]);                                \
    ACCC[1] = MM(afrag[1][6], bf1[2], ACCC[1]);                                \
    ACCC[2] = MM(afrag[2][6], bf1[2], ACCC[2]);                                \
    ACCC[3] = MM(afrag[3][6], bf1[2], ACCC[3]);                                \
    EPI(ACCP, 12); EPI(ACCP, 13);                                              \
    ACCC[0] = MM(afrag[0][7], bf1[3], ACCC[0]);                                \
    ACCC[1] = MM(afrag[1][7], bf1[3], ACCC[1]);                                \
    ACCC[2] = MM(afrag[2][7], bf1[3], ACCC[2]);                                \
    ACCC[3] = MM(afrag[3][7], bf1[3], ACCC[3]);                                \
    EPI(ACCP, 14); EPI(ACCP, 15);                                              \
    bf1[0] = LDV((NEXTB) + 8192);                                              \
    bf1[1] = LDV((NEXTB) + 10240);                                             \
    bf1[2] = LDV((NEXTB) + 12288);                                             \
    bf1[3] = LDV((NEXTB) + 14336);                                             \
  }

  float psum[4][4];
#pragma unroll
  for (int rf = 0; rf < 4; ++rf)
#pragma unroll
    for (int q = 0; q < 4; ++q) psum[rf][q] = 0.f;

  const f32x4 zerov = {0.f, 0.f, 0.f, 0.f};
  bf16x8 bf0[4], bf1[4];
  f32x4 accA[4], accB[4];
  accB[0] = zerov; accB[1] = zerov; accB[2] = zerov; accB[3] = zerov;  // dummy

  STAGE(0);
  STAGE(1);
  STAGE(2);   // 6 loads/wave outstanding
  asm volatile("s_waitcnt vmcnt(4)" ::: "memory");   // own panel-0 loads done
  __builtin_amdgcn_s_barrier();                      // panel 0 fully staged
  {  // preload bf0/bf1 <- cluster (panel 0, cf0)
    const char* pb = smem + vbase;
    bf0[0] = LDV(pb);          bf0[1] = LDV(pb + 2048);
    bf0[2] = LDV(pb + 4096);   bf0[3] = LDV(pb + 6144);
    bf1[0] = LDV(pb + 8192);   bf1[1] = LDV(pb + 10240);
    bf1[2] = LDV(pb + 12288);  bf1[3] = LDV(pb + 14336);
  }

  for (int it = 0; it < 16; ++it) {
    // panels <= it+1 complete at this barrier (needed by cf1's refills).
    if (it <= 13) asm volatile("s_waitcnt vmcnt(2)" ::: "memory");
    else          asm volatile("s_waitcnt vmcnt(0)" ::: "memory");
    __builtin_amdgcn_s_barrier();
    const char* pbase  = smem + ((it & 3) << 14) + vbase;
    const char* npbase = smem + (((it + 1) & 3) << 14) + vbase;
    CLUSTER(accA, accB, pbase + 256);   // (it,cf0); refill <- (it,cf1)
    if (it <= 12) STAGE(it + 3);        // overwrites slot (it-1)&3: retired
    CLUSTER(accB, accA, npbase);        // (it,cf1); refill <- (it+1,cf0)
  }
  // Final epilogue for the last cf1 cluster.
#pragma unroll
  for (int e = 0; e < 16; ++e) { EPI(accB, e); }

  // Reduce over the 16 column-lanes (vary ar, keep g); -1.0 compensates the
  // first-cluster dummy epilogue (exp2(0)=1 added once per element).
#pragma unroll
  for (int rf = 0; rf < 4; ++rf)
#pragma unroll
    for (int q = 0; q < 4; ++q) {
      float s = psum[rf][q] - 1.0f;
      s += __shfl_xor(s, 1);
      s += __shfl_xor(s, 2);
      s += __shfl_xor(s, 4);
      s += __shfl_xor(s, 8);
      if (ar == 0)
        atomicAdd(rowsum + row0 + rf * 16 + g * 4 + q, s);
    }
#undef STAGE
#undef CLUSTER
#undef EPI
#undef MM
#undef LDV
}

// ---------------------------------------------------------------------------
// 3) loss: grid 16 x 512 thr, one row per thread;
//    out[0] (+)= block-partials / N   (out zero-initialized in prep).
// ---------------------------------------------------------------------------
__global__ void __launch_bounds__(512) loss_kernel(
    const float* __restrict__ rowsum, const float* __restrict__ diag,
    float* __restrict__ out) {
  __shared__ float sh[8];
  int i = blockIdx.x * 512 + threadIdx.x;    // exactly covers 8192 rows
  float acc = logf(rowsum[i]) - diag[i];
#pragma unroll
  for (int m = 32; m; m >>= 1) acc += __shfl_xor(acc, m);
  if ((threadIdx.x & 63) == 0) sh[threadIdx.x >> 6] = acc;
  __syncthreads();
  if (threadIdx.x == 0) {
    float t = 0.f;
#pragma unroll
    for (int j = 0; j < 8; ++j) t += sh[j];
    atomicAdd(out, t / (float)N_ROWS);
  }
}

// ---------------------------------------------------------------------------
extern "C" void kernel_launch(void* const* d_in, const int* in_sizes, int n_in,
                              void* d_out, int out_size, void* d_ws, size_t ws_size,
                              hipStream_t stream) {
  const float* anc = (const float*)d_in[0];
  const float* pos = (const float*)d_in[1];
  const float* neg = (const float*)d_in[2];
  char* ws = (char*)d_ws;
  __hip_bfloat16* a_n = (__hip_bfloat16*)ws;                 // [8192][256] bf16 row-major
  __hip_bfloat16* p_k = a_n + (size_t)N_ROWS * DIM;          // k-major panels
  __hip_bfloat16* n_k = p_k + (size_t)N_ROWS * DIM;
  float* diag = (float*)(ws + (size_t)3 * N_ROWS * DIM * 2); // 8192 f32
  float* rowsum = diag + N_ROWS;                             // 8192 f32
  float* out = (float*)d_out;

  prep_kernel<<<2048 + 512, 256, 0, stream>>>(anc, pos, neg, a_n, p_k, n_k, diag, rowsum, out);
  fused_kernel<<<16 * 32, 512, 0, stream>>>(a_n, p_k, n_k, rowsum);
  loss_kernel<<<16, 512, 0, stream>>>(rowsum, diag, out);
}